// Round 13
// baseline (185.005 us; speedup 1.0000x reference)
//
#include <hip/hip_runtime.h>
#include <hip/hip_bf16.h>

constexpr int B = 64, N = 512, F_IN = 256, D = 128, TOPK = 20, HID = 512;

typedef __attribute__((ext_vector_type(8))) short short8_t;   // 8 bf16 = one MFMA frag
typedef __attribute__((ext_vector_type(4))) float f32x4;      // MFMA C/D frag

__device__ inline short f2bs(float f) {   // f32 -> bf16 bits (RNE)
    union { __hip_bfloat16 h; short s; } u; u.h = __float2bfloat16(f); return u.s;
}
__device__ inline float bs2f(short s) {   // bf16 bits -> f32 (shift)
    return __uint_as_float(((unsigned)(unsigned short)s) << 16);
}

// ---- async global->LDS (16B/lane, 1KB/wave-instruction) ----
__device__ inline void gll16(const void* gptr, void* lptr) {
    __builtin_amdgcn_global_load_lds(
        (const __attribute__((address_space(1))) unsigned*)gptr,
        (__attribute__((address_space(3))) unsigned*)lptr, 16, 0, 0);
}

// Stage ROWSx64 bf16 tile (row-major, stride shorts) into XOR-swizzled LDS.
// Chunk ch = 8 rows; lane s -> row ch*8+(s>>3), col16 (s&7)^(s>>3), LDS slot base+s*16.
// Element (row, c16) lives at lds[row*64 + ((c16 ^ (row&7))<<3)].
template<int CH>   // CH = ROWS/8 chunks total; CH/4 per wave
__device__ inline void stage_sw(short* lds, const short* __restrict__ src,
                                int stride, int k0, int wid, int lane) {
    int r8 = lane >> 3, cc = (lane & 7) ^ r8;
    #pragma unroll
    for (int i = 0; i < CH / 4; ++i) {
        int ch = wid * (CH / 4) + i;
        gll16(&src[(size_t)(ch * 8 + r8) * stride + k0 + cc * 8], &lds[ch * 512]);
    }
}

__device__ inline short8_t ld_sw(const short* lds, int row, int c16) {
    return *(const short8_t*)&lds[row * 64 + ((c16 ^ (row & 7)) << 3)];
}

// ---------------- k_wcvt: pre-convert lin_w / w1 / w2 to bf16 (one-time) ----------------
__global__ __launch_bounds__(256) void k_wcvt(const float* __restrict__ lin_w,
                                              const float* __restrict__ w1,
                                              const float* __restrict__ w2,
                                              short* __restrict__ lin_wb,
                                              short* __restrict__ w1b,
                                              short* __restrict__ w2b) {
    int bid = blockIdx.x, t = threadIdx.x;
    const float* src; short* dst; int base;
    if (bid < 16)       { src = lin_w; dst = lin_wb; base = bid * 2048; }
    else if (bid < 144) { src = w1;    dst = w1b;    base = (bid - 16) * 2048; }
    else                { src = w2;    dst = w2b;    base = (bid - 144) * 2048; }
    int idx = base + t * 8;
    float4 x = *(const float4*)(src + idx), y = *(const float4*)(src + idx + 4);
    short8_t v = { f2bs(x.x), f2bs(x.y), f2bs(x.z), f2bs(x.w),
                   f2bs(y.x), f2bs(y.y), f2bs(y.z), f2bs(y.w) };
    *(short8_t*)(dst + idx) = v;
}

// ---------------- K0: row norms + att_em dots + emb passthrough copy ----------------
__global__ void k_norm(const float* __restrict__ W, const float* __restrict__ aei,
                       const float* __restrict__ aej, float* __restrict__ inv_norm,
                       float* __restrict__ ei, float* __restrict__ ej,
                       float* __restrict__ out_emb) {
    int n = blockIdx.x, t = threadIdx.x;  // 128 threads
    float w = W[n * D + t];
    out_emb[n * D + t] = w;
    float s0 = w * w, s1 = w * aei[t], s2 = w * aej[t];
    #pragma unroll
    for (int o = 32; o > 0; o >>= 1) {
        s0 += __shfl_down(s0, o); s1 += __shfl_down(s1, o); s2 += __shfl_down(s2, o);
    }
    __shared__ float r[6];
    if ((t & 63) == 0) { int q = t >> 6; r[q * 3] = s0; r[q * 3 + 1] = s1; r[q * 3 + 2] = s2; }
    __syncthreads();
    if (t == 0) {
        inv_norm[n] = 1.0f / sqrtf(r[0] + r[3]);
        ei[n] = r[1] + r[4];
        ej[n] = r[2] + r[5];
    }
}

// ---------------- K1a: cos tile 32x32, grid 16x16=256 blocks ----------------
__global__ __launch_bounds__(256) void k_cos(const float* __restrict__ W,
                                             const float* __restrict__ inv_norm,
                                             float* __restrict__ cosm) {
    __shared__ float la[32][33];
    __shared__ float lb[32][33];
    int j0 = blockIdx.x * 32, i0 = blockIdx.y * 32, t = threadIdx.x;
    int ix = (t & 15) * 2, jx = (t >> 4) * 2;
    float acc[2][2] = {};
    for (int k0 = 0; k0 < D; k0 += 32) {
        #pragma unroll
        for (int i = 0; i < 4; ++i) {
            int lin = t + i * 256, rl = lin & 31, kk = lin >> 5;
            la[kk][rl] = W[(size_t)(i0 + rl) * D + k0 + kk];
            lb[kk][rl] = W[(size_t)(j0 + rl) * D + k0 + kk];
        }
        __syncthreads();
        #pragma unroll
        for (int kk = 0; kk < 32; ++kk) {
            float a0 = la[kk][ix], a1 = la[kk][ix + 1];
            float b0 = lb[kk][jx], b1 = lb[kk][jx + 1];
            acc[0][0] += a0 * b0; acc[0][1] += a0 * b1;
            acc[1][0] += a1 * b0; acc[1][1] += a1 * b1;
        }
        __syncthreads();
    }
    #pragma unroll
    for (int ii = 0; ii < 2; ++ii) {
        float inv_i = inv_norm[i0 + ix + ii];
        float2 v;
        v.x = acc[ii][0] * inv_i * inv_norm[j0 + jx + 0];
        v.y = acc[ii][1] * inv_i * inv_norm[j0 + jx + 1];
        *(float2*)&cosm[(size_t)(i0 + ix + ii) * N + j0 + jx] = v;
    }
}

// ---------------- K1b: top-20 selection, wave-per-row ----------------
__global__ __launch_bounds__(256) void k_sel(const float* __restrict__ cosm,
                                             int* __restrict__ topk,
                                             float* __restrict__ out_idx) {
    int t = threadIdx.x, wid = t >> 6, lane = t & 63;
    int i = blockIdx.x * 4 + wid;
    float4 p0 = *(const float4*)&cosm[(size_t)i * N + lane * 8];
    float4 p1 = *(const float4*)&cosm[(size_t)i * N + lane * 8 + 4];
    float v[8] = {p0.x, p0.y, p0.z, p0.w, p1.x, p1.y, p1.z, p1.w};
    for (int k = 0; k < TOPK; ++k) {
        float bv = v[0]; int bc = 0;
        #pragma unroll
        for (int c = 1; c < 8; ++c) if (v[c] > bv) { bv = v[c]; bc = c; }
        int bj = lane * 8 + bc;
        #pragma unroll
        for (int o = 1; o < 64; o <<= 1) {
            float ov = __shfl_xor(bv, o);
            int  oj = __shfl_xor(bj, o);
            if (ov > bv || (ov == bv && oj < bj)) { bv = ov; bj = oj; }
        }
        if (lane == 0) {
            topk[i * TOPK + k] = bj;
            out_idx[i * TOPK + k] = (float)bj;
        }
        int oc = bj & 7; bool owner = (bj >> 3) == lane;
        #pragma unroll
        for (int c = 0; c < 8; ++c) if (owner && c == oc) v[c] = -INFINITY;
    }
}

// ---------------- xl: 32n x 128d tile, grid (16, 64) = 1024 blocks (4/CU) ----------
// A: LDS f32 transpose + bf16 repack (padded 72). B: async swizzled staging.
__global__ __launch_bounds__(256) void k_xl(const float* __restrict__ data,
                                            const short* __restrict__ lin_wb,
                                            const float* __restrict__ att_i,
                                            const float* __restrict__ att_j,
                                            const float* __restrict__ ei,
                                            const float* __restrict__ ej,
                                            short* __restrict__ xlb,
                                            float* __restrict__ s_i,
                                            float* __restrict__ s_j) {
    __shared__ float lt[64][33];                       // f32 transpose staging [f][n]
    __shared__ __align__(16) short lds_a[32 * 72];     // padded (repack path)
    __shared__ __align__(16) short lds_b[128 * 64];    // swizzled (async path)
    __shared__ float sred[2][32][2];
    int n0 = blockIdx.x * 32, b = blockIdx.y, t = threadIdx.x;
    int wid = t >> 6, lane = t & 63;
    int wm = (wid & 1) * 16, wn = (wid >> 1) * 64;
    int lr = lane & 15, quad = lane >> 4;
    f32x4 acc[4] = {};
    for (int k0 = 0; k0 < F_IN; k0 += 64) {
        stage_sw<16>(lds_b, lin_wb, F_IN, k0, wid, lane);
        {   // load 64f x 32n data tile, coalesced along n
            int f = t >> 2, ng = (t & 3) * 8;
            const float* p = &data[((size_t)b * F_IN + k0 + f) * N + n0 + ng];
            float4 v0 = *(const float4*)p, v1 = *(const float4*)(p + 4);
            float* q = &lt[f][ng];
            q[0] = v0.x; q[1] = v0.y; q[2] = v0.z; q[3] = v0.w;
            q[4] = v1.x; q[5] = v1.y; q[6] = v1.z; q[7] = v1.w;
        }
        __syncthreads();
        {   // repack transposed: lds_a[n][f] bf16
            int row = t >> 3, seg = t & 7;
            short8_t a;
            #pragma unroll
            for (int j = 0; j < 8; ++j) a[j] = f2bs(lt[seg * 8 + j][row]);
            *(short8_t*)&lds_a[row * 72 + seg * 8] = a;
        }
        __syncthreads();
        #pragma unroll
        for (int kc = 0; kc < 64; kc += 32) {
            int cb = quad + (kc >> 3);
            short8_t a = *(const short8_t*)&lds_a[(wm + lr) * 72 + kc + quad * 8];
            #pragma unroll
            for (int ns = 0; ns < 4; ++ns) {
                short8_t bfr = ld_sw(lds_b, wn + ns * 16 + lr, cb);
                acc[ns] = __builtin_amdgcn_mfma_f32_16x16x32_bf16(a, bfr, acc[ns], 0, 0, 0);
            }
        }
        __syncthreads();
    }
    #pragma unroll
    for (int ns = 0; ns < 4; ++ns) {
        int mb = wm + quad * 4, col = wn + ns * 16 + lr;
        #pragma unroll
        for (int r = 0; r < 4; ++r)
            xlb[((size_t)b * N + n0 + mb + r) * D + col] = f2bs(acc[ns][r]);
    }
    float si4[4], sj4[4];
    #pragma unroll
    for (int r = 0; r < 4; ++r) {
        float si = 0.f, sj = 0.f;
        #pragma unroll
        for (int ns = 0; ns < 4; ++ns) {
            int col = wn + ns * 16 + lr;
            float x = acc[ns][r];
            si += x * att_i[col];
            sj += x * att_j[col];
        }
        si4[r] = si; sj4[r] = sj;
    }
    #pragma unroll
    for (int o = 1; o < 16; o <<= 1) {
        #pragma unroll
        for (int i = 0; i < 4; ++i) {
            si4[i] += __shfl_xor(si4[i], o);
            sj4[i] += __shfl_xor(sj4[i], o);
        }
    }
    if (lr == 0) {
        #pragma unroll
        for (int r = 0; r < 4; ++r) {
            int row = wm + quad * 4 + r;
            sred[wid >> 1][row][0] = si4[r];
            sred[wid >> 1][row][1] = sj4[r];
        }
    }
    __syncthreads();
    if (t < 32) {
        int n = n0 + t;
        s_i[b * N + n] = sred[0][t][0] + sred[1][t][0] + ei[n];
        s_j[b * N + n] = sred[0][t][1] + sred[1][t][1] + ej[n];
    }
}

// ---------------- K4 (round-8 proven v1): softmax(20) + aggregate + BN/gate ----------
__global__ __launch_bounds__(256) void k_attn2(const short* __restrict__ xlb,
                                               const float* __restrict__ emb,
                                               const int* __restrict__ topk,
                                               const float* __restrict__ s_i,
                                               const float* __restrict__ s_j,
                                               const float* __restrict__ gnn_bias,
                                               const float* __restrict__ bn_gamma,
                                               const float* __restrict__ bn_beta,
                                               short* __restrict__ Gt) {
    __shared__ float alph[16][20];
    __shared__ int   js[16][20];
    __shared__ float lt[16][129];
    int n0 = blockIdx.x * 16, b = blockIdx.y, t = threadIdx.x;
    for (int e = t; e < 16 * TOPK; e += 256) {
        int nl = e / TOPK, k = e - nl * TOPK;
        int j = topk[(n0 + nl) * TOPK + k];
        js[nl][k] = j;
        float al = s_i[b * N + n0 + nl] + s_j[b * N + j];
        alph[nl][k] = al >= 0.f ? al : 0.2f * al;
    }
    __syncthreads();
    if (t < 16) {
        float m = -INFINITY;
        for (int k = 0; k < TOPK; ++k) m = fmaxf(m, alph[t][k]);
        float s = 0.f;
        for (int k = 0; k < TOPK; ++k) { float e_ = expf(alph[t][k] - m); alph[t][k] = e_; s += e_; }
        float inv = 1.0f / s;
        for (int k = 0; k < TOPK; ++k) alph[t][k] *= inv;
    }
    __syncthreads();
    {
        int nl = t >> 4, dl = (t & 15) * 8;
        float a[8] = {};
        for (int k = 0; k < TOPK; ++k) {
            float w = alph[nl][k];
            short8_t xv = *(const short8_t*)&xlb[((size_t)b * N + js[nl][k]) * D + dl];
            #pragma unroll
            for (int c = 0; c < 8; ++c) a[c] += w * bs2f(xv[c]);
        }
        const float bnk = 0.9999950000374997f;  // 1/sqrt(1+1e-5)
        #pragma unroll
        for (int c = 0; c < 8; ++c) {
            int d = dl + c;
            float h = (a[c] + gnn_bias[d]) * (bn_gamma[d] * bnk) + bn_beta[d];
            h = fmaxf(h, 0.f);
            lt[nl][d] = h * emb[(n0 + nl) * D + d];
        }
    }
    __syncthreads();
    {
        int d = t >> 1, half = t & 1;
        short8_t v;
        #pragma unroll
        for (int j = 0; j < 8; ++j) v[j] = f2bs(lt[half * 8 + j][d]);
        *(short8_t*)&Gt[((size_t)b * D + d) * N + n0 + half * 8] = v;
    }
}

// ---------------- gemm1: 64d x 64h, BK=64, async swizzled staging ----------------
__global__ __launch_bounds__(256) void k_gemm1(const short* __restrict__ Gt,
                                               const short* __restrict__ w1b,
                                               short* __restrict__ out1) {
    __shared__ __align__(16) short lds_a[64 * 64];
    __shared__ __align__(16) short lds_b[64 * 64];
    int h0 = blockIdx.x * 64, d0 = blockIdx.y * 64, b = blockIdx.z, t = threadIdx.x;
    int wid = t >> 6, lane = t & 63;
    int wm = (wid >> 1) * 32, wn = (wid & 1) * 32;
    int lr = lane & 15, quad = lane >> 4;
    f32x4 acc[2][2] = {};
    const short* Asrc = Gt + ((size_t)b * D + d0) * N;
    const short* Bsrc = w1b + (size_t)h0 * N;
    for (int k0 = 0; k0 < N; k0 += 64) {
        stage_sw<8>(lds_a, Asrc, N, k0, wid, lane);
        stage_sw<8>(lds_b, Bsrc, N, k0, wid, lane);
        __syncthreads();
        #pragma unroll
        for (int kc = 0; kc < 64; kc += 32) {
            int cb = quad + (kc >> 3);
            short8_t af[2], bf[2];
            #pragma unroll
            for (int ms = 0; ms < 2; ++ms) af[ms] = ld_sw(lds_a, wm + ms * 16 + lr, cb);
            #pragma unroll
            for (int ns = 0; ns < 2; ++ns) bf[ns] = ld_sw(lds_b, wn + ns * 16 + lr, cb);
            #pragma unroll
            for (int ms = 0; ms < 2; ++ms)
                #pragma unroll
                for (int ns = 0; ns < 2; ++ns)
                    acc[ms][ns] = __builtin_amdgcn_mfma_f32_16x16x32_bf16(af[ms], bf[ns], acc[ms][ns], 0, 0, 0);
        }
        __syncthreads();
    }
    #pragma unroll
    for (int ms = 0; ms < 2; ++ms)
        #pragma unroll
        for (int ns = 0; ns < 2; ++ns) {
            int mb = d0 + wm + ms * 16 + quad * 4, col = h0 + wn + ns * 16 + lr;
            #pragma unroll
            for (int r = 0; r < 4; ++r)
                out1[((size_t)b * D + mb + r) * HID + col] = f2bs(acc[ms][ns][r]);
        }
}

// ---------------- gemm2: 64d x 64h, BK=64, async swizzled staging ----------------
__global__ __launch_bounds__(256) void k_gemm2(const short* __restrict__ out1,
                                               const short* __restrict__ w2b,
                                               const float* __restrict__ b2,
                                               float* __restrict__ out) {
    __shared__ __align__(16) short lds_a[64 * 64];
    __shared__ __align__(16) short lds_b[64 * 64];
    int h0 = blockIdx.x * 64, d0 = blockIdx.y * 64, b = blockIdx.z, t = threadIdx.x;
    int wid = t >> 6, lane = t & 63;
    int wm = (wid >> 1) * 32, wn = (wid & 1) * 32;
    int lr = lane & 15, quad = lane >> 4;
    f32x4 acc[2][2] = {};
    const short* Asrc = out1 + ((size_t)b * D + d0) * HID;
    const short* Bsrc = w2b + (size_t)h0 * HID;
    for (int k0 = 0; k0 < HID; k0 += 64) {
        stage_sw<8>(lds_a, Asrc, HID, k0, wid, lane);
        stage_sw<8>(lds_b, Bsrc, HID, k0, wid, lane);
        __syncthreads();
        #pragma unroll
        for (int kc = 0; kc < 64; kc += 32) {
            int cb = quad + (kc >> 3);
            short8_t af[2], bf[2];
            #pragma unroll
            for (int ms = 0; ms < 2; ++ms) af[ms] = ld_sw(lds_a, wm + ms * 16 + lr, cb);
            #pragma unroll
            for (int ns = 0; ns < 2; ++ns) bf[ns] = ld_sw(lds_b, wn + ns * 16 + lr, cb);
            #pragma unroll
            for (int ms = 0; ms < 2; ++ms)
                #pragma unroll
                for (int ns = 0; ns < 2; ++ns)
                    acc[ms][ns] = __builtin_amdgcn_mfma_f32_16x16x32_bf16(af[ms], bf[ns], acc[ms][ns], 0, 0, 0);
        }
        __syncthreads();
    }
    #pragma unroll
    for (int ms = 0; ms < 2; ++ms)
        #pragma unroll
        for (int ns = 0; ns < 2; ++ns) {
            int mb = d0 + wm + ms * 16 + quad * 4, col = h0 + wn + ns * 16 + lr;
            float bias = b2[col];
            #pragma unroll
            for (int r = 0; r < 4; ++r)
                out[((size_t)b * D + mb + r) * HID + col] =
                    1.0f / (1.0f + expf(-(acc[ms][ns][r] + bias)));
        }
}

extern "C" void kernel_launch(void* const* d_in, const int* in_sizes, int n_in,
                              void* d_out, int out_size, void* d_ws, size_t ws_size,
                              hipStream_t stream) {
    const float* data     = (const float*)d_in[0];
    const float* emb      = (const float*)d_in[1];
    const float* lin_w    = (const float*)d_in[2];
    const float* att_i    = (const float*)d_in[3];
    const float* att_j    = (const float*)d_in[4];
    const float* att_em_i = (const float*)d_in[5];
    const float* att_em_j = (const float*)d_in[6];
    const float* gnn_bias = (const float*)d_in[7];
    const float* bn_gamma = (const float*)d_in[8];
    const float* bn_beta  = (const float*)d_in[9];
    const float* w1       = (const float*)d_in[10];
    const float* w2       = (const float*)d_in[11];
    const float* b2       = (const float*)d_in[12];
    float* out            = (float*)d_out;   // f32 outputs: [out | emb | topk_idx]

    float* ws       = (float*)d_ws;
    float* inv_norm = ws;                                  // 512 f32
    float* ei       = ws + 512;                            // 512 f32
    float* ej       = ws + 1024;                           // 512 f32
    int*   topk     = (int*)(ws + 1536);                   // 10240 i32
    float* s_i      = ws + 1536 + N * TOPK;                // 32768 f32
    float* s_j      = s_i + B * N;                         // 32768 f32
    short* lin_wb   = (short*)(ws + 77312);                // 32768 bf16 (64 KB)
    short* w1b      = lin_wb + D * F_IN;                   // 262144 bf16 (512 KB)
    short* w2b      = w1b + HID * N;                       // 262144 bf16 (512 KB)
    short* S        = w2b + HID * HID;                     // 24 MB region (16B aligned)
    short* Gt       = S;                                   // B*D*N bf16 = 8 MB
    short* out1     = S + (size_t)B * D * N;               // 8 MB
    short* xlb      = S + 2 * (size_t)B * D * N;           // 8 MB
    float* cosm     = (float*)S;                           // 1 MB, dead before attn2 writes Gt

    float* out_emb = out + (size_t)B * D * HID;
    float* out_idx = out_emb + (size_t)N * D;

    hipLaunchKernelGGL(k_wcvt,  dim3(272),            dim3(256), 0, stream, lin_w, w1, w2, lin_wb, w1b, w2b);
    hipLaunchKernelGGL(k_norm,  dim3(N),              dim3(D),   0, stream, emb, att_em_i, att_em_j, inv_norm, ei, ej, out_emb);
    hipLaunchKernelGGL(k_cos,   dim3(N / 32, N / 32), dim3(256), 0, stream, emb, inv_norm, cosm);
    hipLaunchKernelGGL(k_sel,   dim3(N / 4),          dim3(256), 0, stream, cosm, topk, out_idx);
    hipLaunchKernelGGL(k_xl,    dim3(N / 32, B),      dim3(256), 0, stream, data, lin_wb, att_i, att_j, ei, ej, xlb, s_i, s_j);
    hipLaunchKernelGGL(k_attn2, dim3(N / 16, B),      dim3(256), 0, stream, xlb, emb, topk, s_i, s_j, gnn_bias, bn_gamma, bn_beta, Gt);
    hipLaunchKernelGGL(k_gemm1, dim3(HID / 64, D / 64, B), dim3(256), 0, stream, Gt, w1b, out1);
    hipLaunchKernelGGL(k_gemm2, dim3(HID / 64, D / 64, B), dim3(256), 0, stream, out1, w2b, b2, out);
}

// Round 14
// 180.304 us; speedup vs baseline: 1.0261x; 1.0261x over previous
//
#include <hip/hip_runtime.h>
#include <hip/hip_bf16.h>

constexpr int B = 64, N = 512, F_IN = 256, D = 128, TOPK = 20, HID = 512;

typedef __attribute__((ext_vector_type(8))) short short8_t;   // 8 bf16 = one MFMA frag
typedef __attribute__((ext_vector_type(4))) float f32x4;      // MFMA C/D frag

__device__ inline short f2bs(float f) {   // f32 -> bf16 bits (RNE)
    union { __hip_bfloat16 h; short s; } u; u.h = __float2bfloat16(f); return u.s;
}
__device__ inline float bs2f(short s) {   // bf16 bits -> f32 (shift)
    return __uint_as_float(((unsigned)(unsigned short)s) << 16);
}

// ---- BK=64 staging: tile ROWS x 64 bf16, LDS row stride 72 shorts (proven R8/R12) ----
template<int ITERS>
__device__ inline void stage64_bf16(short* ldst, const short* __restrict__ src,
                                    int stride, int k0, int t) {
    #pragma unroll
    for (int i = 0; i < ITERS; ++i) {
        int lin = t + i * 256, row = lin >> 3, seg = lin & 7;
        *(short8_t*)&ldst[row * 72 + seg * 8] =
            *(const short8_t*)&src[(size_t)row * stride + k0 + seg * 8];
    }
}

template<int MS, int NS>
__device__ inline void mfma_tiles64(const short* lds_a, const short* lds_b,
                                    f32x4 (&acc)[MS][NS], int wm, int wn, int lr, int quad) {
    #pragma unroll
    for (int kc = 0; kc < 64; kc += 32) {
        short8_t af[MS], bf[NS];
        #pragma unroll
        for (int ms = 0; ms < MS; ++ms)
            af[ms] = *(const short8_t*)&lds_a[(wm + ms * 16 + lr) * 72 + kc + quad * 8];
        #pragma unroll
        for (int ns = 0; ns < NS; ++ns)
            bf[ns] = *(const short8_t*)&lds_b[(wn + ns * 16 + lr) * 72 + kc + quad * 8];
        #pragma unroll
        for (int ms = 0; ms < MS; ++ms)
            #pragma unroll
            for (int ns = 0; ns < NS; ++ns)
                acc[ms][ns] = __builtin_amdgcn_mfma_f32_16x16x32_bf16(af[ms], bf[ns], acc[ms][ns], 0, 0, 0);
    }
}

// ---------------- k_prep: fused wcvt (272 blocks) + norm/att_em/emb-copy (256 blocks) ---
// blocks [0,272): convert lin_w/w1/w2 -> bf16. blocks [272,528): 2 nodes each.
__global__ __launch_bounds__(256) void k_prep(const float* __restrict__ lin_w,
                                              const float* __restrict__ w1,
                                              const float* __restrict__ w2,
                                              short* __restrict__ lin_wb,
                                              short* __restrict__ w1b,
                                              short* __restrict__ w2b,
                                              const float* __restrict__ W,
                                              const float* __restrict__ aei,
                                              const float* __restrict__ aej,
                                              float* __restrict__ inv_norm,
                                              float* __restrict__ ei,
                                              float* __restrict__ ej,
                                              float* __restrict__ out_emb) {
    int bid = blockIdx.x, t = threadIdx.x;
    if (bid < 272) {
        const float* src; short* dst; int base;
        if (bid < 16)       { src = lin_w; dst = lin_wb; base = bid * 2048; }
        else if (bid < 144) { src = w1;    dst = w1b;    base = (bid - 16) * 2048; }
        else                { src = w2;    dst = w2b;    base = (bid - 144) * 2048; }
        int idx = base + t * 8;
        float4 x = *(const float4*)(src + idx), y = *(const float4*)(src + idx + 4);
        short8_t v = { f2bs(x.x), f2bs(x.y), f2bs(x.z), f2bs(x.w),
                       f2bs(y.x), f2bs(y.y), f2bs(y.z), f2bs(y.w) };
        *(short8_t*)(dst + idx) = v;
        return;
    }
    // norm part: node pair
    int n = (bid - 272) * 2 + (t >> 7);   // two nodes per block
    int d = t & 127;
    float w = W[n * D + d];
    out_emb[n * D + d] = w;
    float s0 = w * w, s1 = w * aei[d], s2 = w * aej[d];
    #pragma unroll
    for (int o = 32; o > 0; o >>= 1) {
        s0 += __shfl_down(s0, o); s1 += __shfl_down(s1, o); s2 += __shfl_down(s2, o);
    }
    __shared__ float r[4][3];
    int wv = t >> 6;                      // wave id 0..3; node = wv>>1
    if ((t & 63) == 0) { r[wv][0] = s0; r[wv][1] = s1; r[wv][2] = s2; }
    __syncthreads();
    if ((t & 127) == 0) {                 // one finalizer per node
        int q = wv;                       // 0 or 2
        inv_norm[n] = 1.0f / sqrtf(r[q][0] + r[q + 1][0]);
        ei[n] = r[q][1] + r[q + 1][1];
        ej[n] = r[q][2] + r[q + 1][2];
    }
}

// ---------------- K1a: cos tile 32x32, grid 16x16=256 blocks ----------------
__global__ __launch_bounds__(256) void k_cos(const float* __restrict__ W,
                                             const float* __restrict__ inv_norm,
                                             float* __restrict__ cosm) {
    __shared__ float la[32][33];
    __shared__ float lb[32][33];
    int j0 = blockIdx.x * 32, i0 = blockIdx.y * 32, t = threadIdx.x;
    int ix = (t & 15) * 2, jx = (t >> 4) * 2;
    float acc[2][2] = {};
    for (int k0 = 0; k0 < D; k0 += 32) {
        #pragma unroll
        for (int i = 0; i < 4; ++i) {
            int lin = t + i * 256, rl = lin & 31, kk = lin >> 5;
            la[kk][rl] = W[(size_t)(i0 + rl) * D + k0 + kk];
            lb[kk][rl] = W[(size_t)(j0 + rl) * D + k0 + kk];
        }
        __syncthreads();
        #pragma unroll
        for (int kk = 0; kk < 32; ++kk) {
            float a0 = la[kk][ix], a1 = la[kk][ix + 1];
            float b0 = lb[kk][jx], b1 = lb[kk][jx + 1];
            acc[0][0] += a0 * b0; acc[0][1] += a0 * b1;
            acc[1][0] += a1 * b0; acc[1][1] += a1 * b1;
        }
        __syncthreads();
    }
    #pragma unroll
    for (int ii = 0; ii < 2; ++ii) {
        float inv_i = inv_norm[i0 + ix + ii];
        float2 v;
        v.x = acc[ii][0] * inv_i * inv_norm[j0 + jx + 0];
        v.y = acc[ii][1] * inv_i * inv_norm[j0 + jx + 1];
        *(float2*)&cosm[(size_t)(i0 + ix + ii) * N + j0 + jx] = v;
    }
}

// ---------------- K1b: top-20 selection, wave-per-row ----------------
__global__ __launch_bounds__(256) void k_sel(const float* __restrict__ cosm,
                                             int* __restrict__ topk,
                                             float* __restrict__ out_idx) {
    int t = threadIdx.x, wid = t >> 6, lane = t & 63;
    int i = blockIdx.x * 4 + wid;
    float4 p0 = *(const float4*)&cosm[(size_t)i * N + lane * 8];
    float4 p1 = *(const float4*)&cosm[(size_t)i * N + lane * 8 + 4];
    float v[8] = {p0.x, p0.y, p0.z, p0.w, p1.x, p1.y, p1.z, p1.w};
    for (int k = 0; k < TOPK; ++k) {
        float bv = v[0]; int bc = 0;
        #pragma unroll
        for (int c = 1; c < 8; ++c) if (v[c] > bv) { bv = v[c]; bc = c; }
        int bj = lane * 8 + bc;
        #pragma unroll
        for (int o = 1; o < 64; o <<= 1) {
            float ov = __shfl_xor(bv, o);
            int  oj = __shfl_xor(bj, o);
            if (ov > bv || (ov == bv && oj < bj)) { bv = ov; bj = oj; }
        }
        if (lane == 0) {
            topk[i * TOPK + k] = bj;
            out_idx[i * TOPK + k] = (float)bj;
        }
        int oc = bj & 7; bool owner = (bj >> 3) == lane;
        #pragma unroll
        for (int c = 0; c < 8; ++c) if (owner && c == oc) v[c] = -INFINITY;
    }
}

// ---------------- xl (R12 proven): 32n x 128d tile, grid (16, 64) = 1024 blocks -------
__global__ __launch_bounds__(256) void k_xl(const float* __restrict__ data,
                                            const short* __restrict__ lin_wb,
                                            const float* __restrict__ att_i,
                                            const float* __restrict__ att_j,
                                            const float* __restrict__ ei,
                                            const float* __restrict__ ej,
                                            short* __restrict__ xlb,
                                            float* __restrict__ s_i,
                                            float* __restrict__ s_j) {
    __shared__ float lt[64][33];                       // f32 transpose staging [f][n]
    __shared__ __align__(16) short lds_a[32 * 72];
    __shared__ __align__(16) short lds_b[128 * 72];
    __shared__ float sred[2][32][2];
    int n0 = blockIdx.x * 32, b = blockIdx.y, t = threadIdx.x;
    int wid = t >> 6, lane = t & 63;
    int wm = (wid & 1) * 16, wn = (wid >> 1) * 64;
    int lr = lane & 15, quad = lane >> 4;
    f32x4 acc[1][4] = {};
    for (int k0 = 0; k0 < F_IN; k0 += 64) {
        {   // load 64f x 32n data tile, coalesced along n
            int f = t >> 2, ng = (t & 3) * 8;
            const float* p = &data[((size_t)b * F_IN + k0 + f) * N + n0 + ng];
            float4 v0 = *(const float4*)p, v1 = *(const float4*)(p + 4);
            float* q = &lt[f][ng];
            q[0] = v0.x; q[1] = v0.y; q[2] = v0.z; q[3] = v0.w;
            q[4] = v1.x; q[5] = v1.y; q[6] = v1.z; q[7] = v1.w;
        }
        stage64_bf16<4>(lds_b, lin_wb, F_IN, k0, t);
        __syncthreads();
        {   // repack transposed: lds_a[n][f] bf16
            int row = t >> 3, seg = t & 7;
            short8_t a;
            #pragma unroll
            for (int j = 0; j < 8; ++j) a[j] = f2bs(lt[seg * 8 + j][row]);
            *(short8_t*)&lds_a[row * 72 + seg * 8] = a;
        }
        __syncthreads();
        mfma_tiles64<1, 4>(lds_a, lds_b, acc, wm, wn, lr, quad);
        __syncthreads();
    }
    #pragma unroll
    for (int ns = 0; ns < 4; ++ns) {
        int mb = wm + quad * 4, col = wn + ns * 16 + lr;
        #pragma unroll
        for (int r = 0; r < 4; ++r)
            xlb[((size_t)b * N + n0 + mb + r) * D + col] = f2bs(acc[0][ns][r]);
    }
    float si4[4], sj4[4];
    #pragma unroll
    for (int r = 0; r < 4; ++r) {
        float si = 0.f, sj = 0.f;
        #pragma unroll
        for (int ns = 0; ns < 4; ++ns) {
            int col = wn + ns * 16 + lr;
            float x = acc[0][ns][r];
            si += x * att_i[col];
            sj += x * att_j[col];
        }
        si4[r] = si; sj4[r] = sj;
    }
    #pragma unroll
    for (int o = 1; o < 16; o <<= 1) {
        #pragma unroll
        for (int i = 0; i < 4; ++i) {
            si4[i] += __shfl_xor(si4[i], o);
            sj4[i] += __shfl_xor(sj4[i], o);
        }
    }
    if (lr == 0) {
        #pragma unroll
        for (int r = 0; r < 4; ++r) {
            int row = wm + quad * 4 + r;
            sred[wid >> 1][row][0] = si4[r];
            sred[wid >> 1][row][1] = sj4[r];
        }
    }
    __syncthreads();
    if (t < 32) {
        int n = n0 + t;
        s_i[b * N + n] = sred[0][t][0] + sred[1][t][0] + ei[n];
        s_j[b * N + n] = sred[0][t][1] + sred[1][t][1] + ej[n];
    }
}

// ---------------- K4 (proven v1): softmax(20) + aggregate + BN/gate ----------
__global__ __launch_bounds__(256) void k_attn2(const short* __restrict__ xlb,
                                               const float* __restrict__ emb,
                                               const int* __restrict__ topk,
                                               const float* __restrict__ s_i,
                                               const float* __restrict__ s_j,
                                               const float* __restrict__ gnn_bias,
                                               const float* __restrict__ bn_gamma,
                                               const float* __restrict__ bn_beta,
                                               short* __restrict__ Gt) {
    __shared__ float alph[16][20];
    __shared__ int   js[16][20];
    __shared__ float lt[16][129];
    int n0 = blockIdx.x * 16, b = blockIdx.y, t = threadIdx.x;
    for (int e = t; e < 16 * TOPK; e += 256) {
        int nl = e / TOPK, k = e - nl * TOPK;
        int j = topk[(n0 + nl) * TOPK + k];
        js[nl][k] = j;
        float al = s_i[b * N + n0 + nl] + s_j[b * N + j];
        alph[nl][k] = al >= 0.f ? al : 0.2f * al;
    }
    __syncthreads();
    if (t < 16) {
        float m = -INFINITY;
        for (int k = 0; k < TOPK; ++k) m = fmaxf(m, alph[t][k]);
        float s = 0.f;
        for (int k = 0; k < TOPK; ++k) { float e_ = expf(alph[t][k] - m); alph[t][k] = e_; s += e_; }
        float inv = 1.0f / s;
        for (int k = 0; k < TOPK; ++k) alph[t][k] *= inv;
    }
    __syncthreads();
    {
        int nl = t >> 4, dl = (t & 15) * 8;
        float a[8] = {};
        for (int k = 0; k < TOPK; ++k) {
            float w = alph[nl][k];
            short8_t xv = *(const short8_t*)&xlb[((size_t)b * N + js[nl][k]) * D + dl];
            #pragma unroll
            for (int c = 0; c < 8; ++c) a[c] += w * bs2f(xv[c]);
        }
        const float bnk = 0.9999950000374997f;  // 1/sqrt(1+1e-5)
        #pragma unroll
        for (int c = 0; c < 8; ++c) {
            int d = dl + c;
            float h = (a[c] + gnn_bias[d]) * (bn_gamma[d] * bnk) + bn_beta[d];
            h = fmaxf(h, 0.f);
            lt[nl][d] = h * emb[(n0 + nl) * D + d];
        }
    }
    __syncthreads();
    {
        int d = t >> 1, half = t & 1;
        short8_t v;
        #pragma unroll
        for (int j = 0; j < 8; ++j) v[j] = f2bs(lt[half * 8 + j][d]);
        *(short8_t*)&Gt[((size_t)b * D + d) * N + n0 + half * 8] = v;
    }
}

// ---------------- gemm1 (R12 proven): 64d x 64h, BK=64, bf16 weights ----------
__global__ __launch_bounds__(256) void k_gemm1(const short* __restrict__ Gt,
                                               const short* __restrict__ w1b,
                                               short* __restrict__ out1) {
    __shared__ __align__(16) short lds_a[64 * 72];
    __shared__ __align__(16) short lds_b[64 * 72];
    int h0 = blockIdx.x * 64, d0 = blockIdx.y * 64, b = blockIdx.z, t = threadIdx.x;
    int wid = t >> 6, lane = t & 63;
    int wm = (wid >> 1) * 32, wn = (wid & 1) * 32;
    int lr = lane & 15, quad = lane >> 4;
    f32x4 acc[2][2] = {};
    const short* Asrc = Gt + ((size_t)b * D + d0) * N;
    const short* Bsrc = w1b + (size_t)h0 * N;
    for (int k0 = 0; k0 < N; k0 += 64) {
        stage64_bf16<2>(lds_a, Asrc, N, k0, t);
        stage64_bf16<2>(lds_b, Bsrc, N, k0, t);
        __syncthreads();
        mfma_tiles64<2, 2>(lds_a, lds_b, acc, wm, wn, lr, quad);
        __syncthreads();
    }
    #pragma unroll
    for (int ms = 0; ms < 2; ++ms)
        #pragma unroll
        for (int ns = 0; ns < 2; ++ns) {
            int mb = d0 + wm + ms * 16 + quad * 4, col = h0 + wn + ns * 16 + lr;
            #pragma unroll
            for (int r = 0; r < 4; ++r)
                out1[((size_t)b * D + mb + r) * HID + col] = f2bs(acc[ms][ns][r]);
        }
}

// ---------------- gemm2 (R12 proven): 64d x 64h, BK=64, bf16 weights ----------
__global__ __launch_bounds__(256) void k_gemm2(const short* __restrict__ out1,
                                               const short* __restrict__ w2b,
                                               const float* __restrict__ b2,
                                               float* __restrict__ out) {
    __shared__ __align__(16) short lds_a[64 * 72];
    __shared__ __align__(16) short lds_b[64 * 72];
    int h0 = blockIdx.x * 64, d0 = blockIdx.y * 64, b = blockIdx.z, t = threadIdx.x;
    int wid = t >> 6, lane = t & 63;
    int wm = (wid >> 1) * 32, wn = (wid & 1) * 32;
    int lr = lane & 15, quad = lane >> 4;
    f32x4 acc[2][2] = {};
    const short* Asrc = out1 + ((size_t)b * D + d0) * HID;
    const short* Bsrc = w2b + (size_t)h0 * HID;
    for (int k0 = 0; k0 < HID; k0 += 64) {
        stage64_bf16<2>(lds_a, Asrc, HID, k0, t);
        stage64_bf16<2>(lds_b, Bsrc, HID, k0, t);
        __syncthreads();
        mfma_tiles64<2, 2>(lds_a, lds_b, acc, wm, wn, lr, quad);
        __syncthreads();
    }
    #pragma unroll
    for (int ms = 0; ms < 2; ++ms)
        #pragma unroll
        for (int ns = 0; ns < 2; ++ns) {
            int mb = d0 + wm + ms * 16 + quad * 4, col = h0 + wn + ns * 16 + lr;
            float bias = b2[col];
            #pragma unroll
            for (int r = 0; r < 4; ++r)
                out[((size_t)b * D + mb + r) * HID + col] =
                    1.0f / (1.0f + expf(-(acc[ms][ns][r] + bias)));
        }
}

extern "C" void kernel_launch(void* const* d_in, const int* in_sizes, int n_in,
                              void* d_out, int out_size, void* d_ws, size_t ws_size,
                              hipStream_t stream) {
    const float* data     = (const float*)d_in[0];
    const float* emb      = (const float*)d_in[1];
    const float* lin_w    = (const float*)d_in[2];
    const float* att_i    = (const float*)d_in[3];
    const float* att_j    = (const float*)d_in[4];
    const float* att_em_i = (const float*)d_in[5];
    const float* att_em_j = (const float*)d_in[6];
    const float* gnn_bias = (const float*)d_in[7];
    const float* bn_gamma = (const float*)d_in[8];
    const float* bn_beta  = (const float*)d_in[9];
    const float* w1       = (const float*)d_in[10];
    const float* w2       = (const float*)d_in[11];
    const float* b2       = (const float*)d_in[12];
    float* out            = (float*)d_out;   // f32 outputs: [out | emb | topk_idx]

    float* ws       = (float*)d_ws;
    float* inv_norm = ws;                                  // 512 f32
    float* ei       = ws + 512;                            // 512 f32
    float* ej       = ws + 1024;                           // 512 f32
    int*   topk     = (int*)(ws + 1536);                   // 10240 i32
    float* s_i      = ws + 1536 + N * TOPK;                // 32768 f32
    float* s_j      = s_i + B * N;                         // 32768 f32
    short* lin_wb   = (short*)(ws + 77312);                // 32768 bf16 (64 KB)
    short* w1b      = lin_wb + D * F_IN;                   // 262144 bf16 (512 KB)
    short* w2b      = w1b + HID * N;                       // 262144 bf16 (512 KB)
    short* S        = w2b + HID * HID;                     // 24 MB region (16B aligned)
    short* Gt       = S;                                   // B*D*N bf16 = 8 MB
    short* out1     = S + (size_t)B * D * N;               // 8 MB
    short* xlb      = S + 2 * (size_t)B * D * N;           // 8 MB
    float* cosm     = (float*)S;                           // 1 MB, dead before attn2 writes Gt

    float* out_emb = out + (size_t)B * D * HID;
    float* out_idx = out_emb + (size_t)N * D;

    hipLaunchKernelGGL(k_prep,  dim3(528),            dim3(256), 0, stream,
                       lin_w, w1, w2, lin_wb, w1b, w2b,
                       emb, att_em_i, att_em_j, inv_norm, ei, ej, out_emb);
    hipLaunchKernelGGL(k_cos,   dim3(N / 32, N / 32), dim3(256), 0, stream, emb, inv_norm, cosm);
    hipLaunchKernelGGL(k_sel,   dim3(N / 4),          dim3(256), 0, stream, cosm, topk, out_idx);
    hipLaunchKernelGGL(k_xl,    dim3(N / 32, B),      dim3(256), 0, stream, data, lin_wb, att_i, att_j, ei, ej, xlb, s_i, s_j);
    hipLaunchKernelGGL(k_attn2, dim3(N / 16, B),      dim3(256), 0, stream, xlb, emb, topk, s_i, s_j, gnn_bias, bn_gamma, bn_beta, Gt);
    hipLaunchKernelGGL(k_gemm1, dim3(HID / 64, D / 64, B), dim3(256), 0, stream, Gt, w1b, out1);
    hipLaunchKernelGGL(k_gemm2, dim3(HID / 64, D / 64, B), dim3(256), 0, stream, out1, w2b, b2, out);
}